// Round 11
// baseline (228.801 us; speedup 1.0000x reference)
//
#include <hip/hip_runtime.h>
#include <hip/hip_bf16.h>
#include <math.h>

#define RR 64
#define CC 32
#define NPTS (4*262144)

typedef __attribute__((ext_vector_type(8))) short short8;
typedef __attribute__((ext_vector_type(4))) float f32x4;
typedef __attribute__((ext_vector_type(4))) unsigned int u32x4;

static __device__ inline ushort f2bf(float x) {
    return __builtin_bit_cast(ushort, __float2bfloat16(x));
}
static __device__ inline uint32_t pk2(float a, float b) {
    return (uint32_t)f2bf(a) | ((uint32_t)f2bf(b) << 16);
}
static __device__ inline float relu(float x) { return fmaxf(x, 0.0f); }

// ws layout:
//   float  Pcl[3*64*64*32]   @ 0          channel-last fp32 planes [p][y][x][ch]
//   ushort W1T[24576]        @ 393216 f   layer1 A-frag table [nt][p][lane][e]
//   ushort W2T[16384]        follows      layer2 A-frag table [nt2][kt2][lane][e]
//   float  CWS[896]          follows      BC[256]=db1|rb1 | db2[128] | dW3[128] | rW2[384]
// W1T..CWS = 85504 B, staged to LDS once per block.

__global__ void prepass(const float* __restrict__ planes,
                        const float* __restrict__ dW1, const float* __restrict__ rW1,
                        const float* __restrict__ dW2,
                        const float* __restrict__ db1, const float* __restrict__ rb1,
                        const float* __restrict__ db2, const float* __restrict__ dW3,
                        const float* __restrict__ rW2,
                        float* __restrict__ ws) {
    int tid = blockIdx.x * blockDim.x + threadIdx.x;
    ushort* W1T = (ushort*)(ws + 393216);
    ushort* W2T = W1T + 24576;
    float*  CWS = ws + 393216 + 20480;

    if (tid < 3 * CC * RR * RR) {
        int x = tid % RR, y = (tid / RR) % RR, ch = (tid / (RR * RR)) % CC, p = tid / (CC * RR * RR);
        ws[((p * RR + y) * RR + x) * CC + ch] = planes[tid];
    }
    if (tid < 24576) {   // W1T: tid = ((nt*3+p)*64 + l)*8 + e
        int e = tid & 7, l = (tid >> 3) & 63, rem = tid >> 9;
        int p = rem % 3, nt = rem / 3;
        int j = nt * 16 + (l & 15);
        int k = p * 32 + (l >> 4) * 8 + e;
        float v = (j < 128) ? dW1[j * 96 + k] : rW1[(j - 128) * 96 + k];
        W1T[tid] = f2bf(v);
    }
    if (tid < 16384) {   // W2T: tid = ((nt2*4+kt2)*64 + l)*8 + e
        int e = tid & 7, l = (tid >> 3) & 63, rem = tid >> 9;
        int kt2 = rem & 3, nt2 = rem >> 2;
        int j2 = nt2 * 16 + (l & 15);
        int k = kt2 * 32 + (l >> 4) * 8 + e;
        W2T[tid] = f2bf(dW2[j2 * 128 + k]);
    }
    if (tid < 256) CWS[tid]       = (tid < 128) ? db1[tid] : rb1[tid - 128];
    if (tid < 128) CWS[256 + tid] = db2[tid];
    if (tid < 128) CWS[384 + tid] = dW3[tid];
    if (tid < 384) CWS[512 + tid] = rW2[tid];
}

// Bilinear-sample 8 channels (8g..8g+7) of one plane at (cx,cy), packed as a
// bf16 MFMA B-fragment. Pure named scalars -> registers.
static __device__ inline short8 sample_frag(const float* __restrict__ P,
                                            int plane_base, float cx, float cy, int g8) {
    float ix = (cx + 1.0f) * 31.5f; ix = fminf(fmaxf(ix, 0.0f), 63.0f);
    float iy = (cy + 1.0f) * 31.5f; iy = fminf(fmaxf(iy, 0.0f), 63.0f);
    int x0 = (int)ix, y0 = (int)iy;
    int x1 = min(x0 + 1, 63), y1 = min(y0 + 1, 63);
    float wx = ix - (float)x0, wy = iy - (float)y0;
    float w00 = (1.0f - wx) * (1.0f - wy), w01 = wx * (1.0f - wy);
    float w10 = (1.0f - wx) * wy,          w11 = wx * wy;
    int b00 = plane_base + (y0 * 64 + x0) * 32 + g8;
    int b01 = plane_base + (y0 * 64 + x1) * 32 + g8;
    int b10 = plane_base + (y1 * 64 + x0) * 32 + g8;
    int b11 = plane_base + (y1 * 64 + x1) * 32 + g8;
    f32x4 a0 = *(const f32x4*)(P + b00), a1 = *(const f32x4*)(P + b00 + 4);
    f32x4 c0 = *(const f32x4*)(P + b01), c1 = *(const f32x4*)(P + b01 + 4);
    f32x4 d0 = *(const f32x4*)(P + b10), d1 = *(const f32x4*)(P + b10 + 4);
    f32x4 e0 = *(const f32x4*)(P + b11), e1 = *(const f32x4*)(P + b11 + 4);
    float f0 = w00 * a0[0] + w01 * c0[0] + w10 * d0[0] + w11 * e0[0];
    float f1 = w00 * a0[1] + w01 * c0[1] + w10 * d0[1] + w11 * e0[1];
    float f2 = w00 * a0[2] + w01 * c0[2] + w10 * d0[2] + w11 * e0[2];
    float f3 = w00 * a0[3] + w01 * c0[3] + w10 * d0[3] + w11 * e0[3];
    float f4 = w00 * a1[0] + w01 * c1[0] + w10 * d1[0] + w11 * e1[0];
    float f5 = w00 * a1[1] + w01 * c1[1] + w10 * d1[1] + w11 * e1[1];
    float f6 = w00 * a1[2] + w01 * c1[2] + w10 * d1[2] + w11 * e1[2];
    float f7 = w00 * a1[3] + w01 * c1[3] + w10 * d1[3] + w11 * e1[3];
    u32x4 uu;
    uu[0] = pk2(f0, f1); uu[1] = pk2(f2, f3);
    uu[2] = pk2(f4, f5); uu[3] = pk2(f6, f7);
    return __builtin_bit_cast(short8, uu);
}

#define MFMA(a, b, c) __builtin_amdgcn_mfma_f32_16x16x32_bf16((a), (b), (c), 0, 0, 0)

// Density layer-1 tile nt for BOTH point halves: one A-frag read feeds 2 MFMAs.
// A-half result -> H (LDS); B-half result -> two named u32 regs (written later).
#define DNT(nt, HB0, HB1) { \
    const ushort* wp_ = W1L + (nt) * 1536 + lane * 8; \
    short8 a0_ = *(const short8*)(wp_); \
    short8 a1_ = *(const short8*)(wp_ + 512); \
    short8 a2_ = *(const short8*)(wp_ + 1024); \
    f32x4 accA_ = {0.f,0.f,0.f,0.f}, accB_ = {0.f,0.f,0.f,0.f}; \
    accA_ = MFMA(a0_, bfA0, accA_); accB_ = MFMA(a0_, bfB0, accB_); \
    accA_ = MFMA(a1_, bfA1, accA_); accB_ = MFMA(a1_, bfB1, accB_); \
    accA_ = MFMA(a2_, bfA2, accA_); accB_ = MFMA(a2_, bfB2, accB_); \
    f32x4 bb_ = *(const f32x4*)(Cl + (nt) * 16 + 4 * g); \
    uint2 wA_; \
    wA_.x = pk2(relu(accA_[0] + bb_[0]), relu(accA_[1] + bb_[1])); \
    wA_.y = pk2(relu(accA_[2] + bb_[2]), relu(accA_[3] + bb_[3])); \
    *(uint2*)(&H[c][16 * (nt) + 4 * g]) = wA_; \
    HB0 = pk2(relu(accB_[0] + bb_[0]), relu(accB_[1] + bb_[1])); \
    HB1 = pk2(relu(accB_[2] + bb_[2]), relu(accB_[3] + bb_[3])); }

#define HWB(nt, HB0, HB1) { \
    uint2 t_; t_.x = HB0; t_.y = HB1; \
    *(uint2*)(&H[c][16 * (nt) + 4 * g]) = t_; }

#define LDSFENCE { asm volatile("s_waitcnt lgkmcnt(0)" ::: "memory"); \
                   __builtin_amdgcn_sched_barrier(0); }

// NOTE: second __launch_bounds__ arg behaves as min BLOCKS per CU on this
// toolchain. (1024,1): 16 waves/CU = 4/SIMD -> 128-VGPR cap. Live set ~110.
__global__ __launch_bounds__(1024, 1)
void nerf_mfma(const float* __restrict__ points, const float* __restrict__ ws,
               const float* __restrict__ db3g, const float* __restrict__ rb2g,
               float* __restrict__ rgb_out, float* __restrict__ den_out) {
    // LDS: weights+consts 85504 B + per-wave H 16*16*136*2 = 69632 B -> 155136 B
    __shared__ __align__(16) ushort SB[42752];
    __shared__ __align__(16) ushort Hs[16][16][136];

    const float* P = ws;
    int tid = threadIdx.x;

    // ---- stage weight tables + consts into LDS (once per block) ----
    {
        const u32x4* src = (const u32x4*)(ws + 393216);
        u32x4* dst = (u32x4*)SB;
        for (int j = tid; j < 5344; j += 1024) dst[j] = src[j];
    }
    __syncthreads();

    const ushort* W1L = SB;                          // 24576 ushorts
    const ushort* W2L = SB + 24576;                  // 16384 ushorts
    const float*  Cl  = (const float*)(SB + 40960);  // BC | db2 | dW3 | rW2

    int wid = tid >> 6, lane = tid & 63;
    int c = lane & 15, g = lane >> 4;
    int g8 = 8 * g;
    ushort (*H)[136] = Hs[wid];
    int gw = blockIdx.x * 16 + wid;     // 16384 waves, 2 tiles each, 32 pts/tile

    float b3  = db3g[0];
    float rb0 = rb2g[0], rb1v = rb2g[1], rb2v = rb2g[2];

    for (int it = 0; it < 2; ++it) {
        int pbase = (gw * 2 + it) * 32;

        // ---- features: lane (c,g) -> channels 8g..8g+7, points A=c, B=c+16 ----
        int ptA = pbase + c, ptB = pbase + c + 16;
        float xa = points[ptA * 3 + 0], ya = points[ptA * 3 + 1], za = points[ptA * 3 + 2];
        float xb = points[ptB * 3 + 0], yb = points[ptB * 3 + 1], zb = points[ptB * 3 + 2];
        short8 bfA0 = sample_frag(P, 0,      xa, ya, g8);
        short8 bfA1 = sample_frag(P, 131072, xa, za, g8);
        short8 bfA2 = sample_frag(P, 262144, ya, za, g8);
        short8 bfB0 = sample_frag(P, 0,      xb, yb, g8);
        short8 bfB1 = sample_frag(P, 131072, xb, zb, g8);
        short8 bfB2 = sample_frag(P, 262144, yb, zb, g8);

        // ---- layer1 rgb half (nt=8..15): fold rW2 immediately; w-reads shared ----
        float r0A = 0.f, r1A = 0.f, r2A = 0.f, r0B = 0.f, r1B = 0.f, r2B = 0.f;
        #pragma unroll 4
        for (int nt = 8; nt < 16; ++nt) {
            const ushort* wp = W1L + nt * 1536 + lane * 8;
            short8 a0 = *(const short8*)(wp);
            short8 a1 = *(const short8*)(wp + 512);
            short8 a2 = *(const short8*)(wp + 1024);
            f32x4 accA = {0.f,0.f,0.f,0.f}, accB = {0.f,0.f,0.f,0.f};
            accA = MFMA(a0, bfA0, accA); accB = MFMA(a0, bfB0, accB);
            accA = MFMA(a1, bfA1, accA); accB = MFMA(a1, bfB1, accB);
            accA = MFMA(a2, bfA2, accA); accB = MFMA(a2, bfB2, accB);
            int jo = (nt - 8) * 16 + 4 * g;
            f32x4 bb = *(const f32x4*)(Cl + 128 + jo);
            f32x4 w0 = *(const f32x4*)(Cl + 512 + jo);
            f32x4 w1 = *(const f32x4*)(Cl + 640 + jo);
            f32x4 w2 = *(const f32x4*)(Cl + 768 + jo);
            #pragma unroll
            for (int r = 0; r < 4; ++r) {
                float vA = relu(accA[r] + bb[r]);
                float vB = relu(accB[r] + bb[r]);
                r0A = fmaf(w0[r], vA, r0A); r0B = fmaf(w0[r], vB, r0B);
                r1A = fmaf(w1[r], vA, r1A); r1B = fmaf(w1[r], vB, r1B);
                r2A = fmaf(w2[r], vA, r2A); r2B = fmaf(w2[r], vB, r2B);
            }
        }
        // rgb heads now (kills racc early)
        {
            float v0 = r0A, v1 = r1A, v2 = r2A;
            v0 += __shfl_xor(v0, 16, 64); v0 += __shfl_xor(v0, 32, 64);
            v1 += __shfl_xor(v1, 16, 64); v1 += __shfl_xor(v1, 32, 64);
            v2 += __shfl_xor(v2, 16, 64); v2 += __shfl_xor(v2, 32, 64);
            if (g == 0) {
                rgb_out[ptA * 3 + 0] = 1.0f / (1.0f + expf(-(v0 + rb0)));
                rgb_out[ptA * 3 + 1] = 1.0f / (1.0f + expf(-(v1 + rb1v)));
                rgb_out[ptA * 3 + 2] = 1.0f / (1.0f + expf(-(v2 + rb2v)));
            }
        }
        {
            float v0 = r0B, v1 = r1B, v2 = r2B;
            v0 += __shfl_xor(v0, 16, 64); v0 += __shfl_xor(v0, 32, 64);
            v1 += __shfl_xor(v1, 16, 64); v1 += __shfl_xor(v1, 32, 64);
            v2 += __shfl_xor(v2, 16, 64); v2 += __shfl_xor(v2, 32, 64);
            if (g == 0) {
                rgb_out[ptB * 3 + 0] = 1.0f / (1.0f + expf(-(v0 + rb0)));
                rgb_out[ptB * 3 + 1] = 1.0f / (1.0f + expf(-(v1 + rb1v)));
                rgb_out[ptB * 3 + 2] = 1.0f / (1.0f + expf(-(v2 + rb2v)));
            }
        }

        // ---- layer1 density half (nt=0..7): A -> H, B -> named regs ----
        unsigned hB0a, hB0b, hB1a, hB1b, hB2a, hB2b, hB3a, hB3b;
        unsigned hB4a, hB4b, hB5a, hB5b, hB6a, hB6b, hB7a, hB7b;
        DNT(0, hB0a, hB0b) DNT(1, hB1a, hB1b) DNT(2, hB2a, hB2b) DNT(3, hB3a, hB3b)
        DNT(4, hB4a, hB4b) DNT(5, hB5a, hB5b) DNT(6, hB6a, hB6b) DNT(7, hB7a, hB7b)

        LDSFENCE
        // A-half layer-2 B-frags
        short8 b2A0 = *(const short8*)(&H[c][g8]);
        short8 b2A1 = *(const short8*)(&H[c][32 + g8]);
        short8 b2A2 = *(const short8*)(&H[c][64 + g8]);
        short8 b2A3 = *(const short8*)(&H[c][96 + g8]);
        LDSFENCE   // A reads complete before B overwrites
        HWB(0, hB0a, hB0b) HWB(1, hB1a, hB1b) HWB(2, hB2a, hB2b) HWB(3, hB3a, hB3b)
        HWB(4, hB4a, hB4b) HWB(5, hB5a, hB5b) HWB(6, hB6a, hB6b) HWB(7, hB7a, hB7b)
        LDSFENCE
        // B-half layer-2 B-frags
        short8 b2B0 = *(const short8*)(&H[c][g8]);
        short8 b2B1 = *(const short8*)(&H[c][32 + g8]);
        short8 b2B2 = *(const short8*)(&H[c][64 + g8]);
        short8 b2B3 = *(const short8*)(&H[c][96 + g8]);

        // ---- layer2 + density fold: one A-frag read feeds 2 MFMAs ----
        float daccA = 0.f, daccB = 0.f;
        #pragma unroll 2
        for (int nt2 = 0; nt2 < 8; ++nt2) {
            const ushort* wp = W2L + nt2 * 2048 + lane * 8;
            short8 a0 = *(const short8*)(wp);
            short8 a1 = *(const short8*)(wp + 512);
            short8 a2 = *(const short8*)(wp + 1024);
            short8 a3 = *(const short8*)(wp + 1536);
            f32x4 accA = {0.f,0.f,0.f,0.f}, accB = {0.f,0.f,0.f,0.f};
            accA = MFMA(a0, b2A0, accA); accB = MFMA(a0, b2B0, accB);
            accA = MFMA(a1, b2A1, accA); accB = MFMA(a1, b2B1, accB);
            accA = MFMA(a2, b2A2, accA); accB = MFMA(a2, b2B2, accB);
            accA = MFMA(a3, b2A3, accA); accB = MFMA(a3, b2B3, accB);
            f32x4 bb = *(const f32x4*)(Cl + 256 + nt2 * 16 + 4 * g);
            f32x4 w3 = *(const f32x4*)(Cl + 384 + nt2 * 16 + 4 * g);
            #pragma unroll
            for (int r = 0; r < 4; ++r) {
                daccA = fmaf(w3[r], relu(accA[r] + bb[r]), daccA);
                daccB = fmaf(w3[r], relu(accB[r] + bb[r]), daccB);
            }
        }

        // ---- density heads ----
        {
            float v = daccA; v += __shfl_xor(v, 16, 64); v += __shfl_xor(v, 32, 64); v += b3;
            float sp = fmaxf(v, 0.0f) + log1pf(expf(-fabsf(v)));
            if (g == 0) den_out[ptA] = sp;
        }
        {
            float v = daccB; v += __shfl_xor(v, 16, 64); v += __shfl_xor(v, 32, 64); v += b3;
            float sp = fmaxf(v, 0.0f) + log1pf(expf(-fabsf(v)));
            if (g == 0) den_out[ptB] = sp;
        }

        asm volatile("" ::: "memory");   // keep next tile's LDS writes after this tile's reads
    }
}

extern "C" void kernel_launch(void* const* d_in, const int* in_sizes, int n_in,
                              void* d_out, int out_size, void* d_ws, size_t ws_size,
                              hipStream_t stream) {
    const float* points = (const float*)d_in[0];
    const float* planes = (const float*)d_in[1];
    const float* dW1    = (const float*)d_in[2];
    const float* db1    = (const float*)d_in[3];
    const float* dW2    = (const float*)d_in[4];
    const float* db2    = (const float*)d_in[5];
    const float* dW3    = (const float*)d_in[6];
    const float* db3    = (const float*)d_in[7];
    const float* rW1    = (const float*)d_in[8];
    const float* rb1    = (const float*)d_in[9];
    const float* rW2    = (const float*)d_in[10];
    const float* rb2    = (const float*)d_in[11];

    float* out     = (float*)d_out;
    float* rgb_out = out;                 // 3*NPTS floats
    float* den_out = out + 3 * NPTS;      // NPTS floats
    float* ws      = (float*)d_ws;

    prepass<<<1536, 256, 0, stream>>>(planes, dW1, rW1, dW2, db1, rb1,
                                      db2, dW3, rW2, ws);
    nerf_mfma<<<1024, 1024, 0, stream>>>(points, ws, db3, rb2, rgb_out, den_out);
}

// Round 12
// 222.920 us; speedup vs baseline: 1.0264x; 1.0264x over previous
//
#include <hip/hip_runtime.h>
#include <hip/hip_bf16.h>
#include <math.h>

#define RR 64
#define CC 32
#define NPTS (4*262144)

typedef __attribute__((ext_vector_type(8))) short short8;
typedef __attribute__((ext_vector_type(4))) float f32x4;
typedef __attribute__((ext_vector_type(4))) unsigned int u32x4;

static __device__ inline ushort f2bf(float x) {
    return __builtin_bit_cast(ushort, __float2bfloat16(x));
}
static __device__ inline uint32_t pk2(float a, float b) {
    return (uint32_t)f2bf(a) | ((uint32_t)f2bf(b) << 16);
}
static __device__ inline float relu(float x) { return fmaxf(x, 0.0f); }

// ws layout:
//   float  Pcl[3*64*64*32]   @ 0          channel-last fp32 planes [p][y][x][ch]
//   ushort W1T[24576]        @ 393216 f   layer1 A-frag table [nt][p][lane][e]
//   ushort W2T[16384]        follows      layer2 A-frag table [nt2][kt2][lane][e]
//   float  CWS[896]          follows      BC[256]=db1|rb1 | db2[128] | dW3[128] | rW2[384]
// W1T..CWS = 85504 B, staged to LDS once per block.

__global__ void prepass(const float* __restrict__ planes,
                        const float* __restrict__ dW1, const float* __restrict__ rW1,
                        const float* __restrict__ dW2,
                        const float* __restrict__ db1, const float* __restrict__ rb1,
                        const float* __restrict__ db2, const float* __restrict__ dW3,
                        const float* __restrict__ rW2,
                        float* __restrict__ ws) {
    int tid = blockIdx.x * blockDim.x + threadIdx.x;
    ushort* W1T = (ushort*)(ws + 393216);
    ushort* W2T = W1T + 24576;
    float*  CWS = ws + 393216 + 20480;

    if (tid < 3 * CC * RR * RR) {
        int x = tid % RR, y = (tid / RR) % RR, ch = (tid / (RR * RR)) % CC, p = tid / (CC * RR * RR);
        ws[((p * RR + y) * RR + x) * CC + ch] = planes[tid];
    }
    if (tid < 24576) {   // W1T: tid = ((nt*3+p)*64 + l)*8 + e
        int e = tid & 7, l = (tid >> 3) & 63, rem = tid >> 9;
        int p = rem % 3, nt = rem / 3;
        int j = nt * 16 + (l & 15);
        int k = p * 32 + (l >> 4) * 8 + e;
        float v = (j < 128) ? dW1[j * 96 + k] : rW1[(j - 128) * 96 + k];
        W1T[tid] = f2bf(v);
    }
    if (tid < 16384) {   // W2T: tid = ((nt2*4+kt2)*64 + l)*8 + e
        int e = tid & 7, l = (tid >> 3) & 63, rem = tid >> 9;
        int kt2 = rem & 3, nt2 = rem >> 2;
        int j2 = nt2 * 16 + (l & 15);
        int k = kt2 * 32 + (l >> 4) * 8 + e;
        W2T[tid] = f2bf(dW2[j2 * 128 + k]);
    }
    if (tid < 256) CWS[tid]       = (tid < 128) ? db1[tid] : rb1[tid - 128];
    if (tid < 128) CWS[256 + tid] = db2[tid];
    if (tid < 128) CWS[384 + tid] = dW3[tid];
    if (tid < 384) CWS[512 + tid] = rW2[tid];
}

// Bilinear-sample 8 channels (8g..8g+7) of one plane at (cx,cy), packed as a
// bf16 MFMA B-fragment. Pure named scalars -> registers.
static __device__ inline short8 sample_frag(const float* __restrict__ P,
                                            int plane_base, float cx, float cy, int g8) {
    float ix = (cx + 1.0f) * 31.5f; ix = fminf(fmaxf(ix, 0.0f), 63.0f);
    float iy = (cy + 1.0f) * 31.5f; iy = fminf(fmaxf(iy, 0.0f), 63.0f);
    int x0 = (int)ix, y0 = (int)iy;
    int x1 = min(x0 + 1, 63), y1 = min(y0 + 1, 63);
    float wx = ix - (float)x0, wy = iy - (float)y0;
    float w00 = (1.0f - wx) * (1.0f - wy), w01 = wx * (1.0f - wy);
    float w10 = (1.0f - wx) * wy,          w11 = wx * wy;
    int b00 = plane_base + (y0 * 64 + x0) * 32 + g8;
    int b01 = plane_base + (y0 * 64 + x1) * 32 + g8;
    int b10 = plane_base + (y1 * 64 + x0) * 32 + g8;
    int b11 = plane_base + (y1 * 64 + x1) * 32 + g8;
    f32x4 a0 = *(const f32x4*)(P + b00), a1 = *(const f32x4*)(P + b00 + 4);
    f32x4 c0 = *(const f32x4*)(P + b01), c1 = *(const f32x4*)(P + b01 + 4);
    f32x4 d0 = *(const f32x4*)(P + b10), d1 = *(const f32x4*)(P + b10 + 4);
    f32x4 e0 = *(const f32x4*)(P + b11), e1 = *(const f32x4*)(P + b11 + 4);
    float f0 = w00 * a0[0] + w01 * c0[0] + w10 * d0[0] + w11 * e0[0];
    float f1 = w00 * a0[1] + w01 * c0[1] + w10 * d0[1] + w11 * e0[1];
    float f2 = w00 * a0[2] + w01 * c0[2] + w10 * d0[2] + w11 * e0[2];
    float f3 = w00 * a0[3] + w01 * c0[3] + w10 * d0[3] + w11 * e0[3];
    float f4 = w00 * a1[0] + w01 * c1[0] + w10 * d1[0] + w11 * e1[0];
    float f5 = w00 * a1[1] + w01 * c1[1] + w10 * d1[1] + w11 * e1[1];
    float f6 = w00 * a1[2] + w01 * c1[2] + w10 * d1[2] + w11 * e1[2];
    float f7 = w00 * a1[3] + w01 * c1[3] + w10 * d1[3] + w11 * e1[3];
    u32x4 uu;
    uu[0] = pk2(f0, f1); uu[1] = pk2(f2, f3);
    uu[2] = pk2(f4, f5); uu[3] = pk2(f6, f7);
    return __builtin_bit_cast(short8, uu);
}

#define MFMA(a, b, c) __builtin_amdgcn_mfma_f32_16x16x32_bf16((a), (b), (c), 0, 0, 0)

// Density layer-1 tile nt for BOTH point halves: one A-frag read feeds 2 MFMAs.
// A-half result -> H (LDS); B-half result -> two named u32 regs (written later).
#define DNT(nt, HB0, HB1) { \
    const ushort* wp_ = W1L + (nt) * 1536 + lane * 8; \
    short8 a0_ = *(const short8*)(wp_); \
    short8 a1_ = *(const short8*)(wp_ + 512); \
    short8 a2_ = *(const short8*)(wp_ + 1024); \
    f32x4 accA_ = {0.f,0.f,0.f,0.f}, accB_ = {0.f,0.f,0.f,0.f}; \
    accA_ = MFMA(a0_, bfA0, accA_); accB_ = MFMA(a0_, bfB0, accB_); \
    accA_ = MFMA(a1_, bfA1, accA_); accB_ = MFMA(a1_, bfB1, accB_); \
    accA_ = MFMA(a2_, bfA2, accA_); accB_ = MFMA(a2_, bfB2, accB_); \
    f32x4 bb_ = *(const f32x4*)(Cl + (nt) * 16 + 4 * g); \
    uint2 wA_; \
    wA_.x = pk2(relu(accA_[0] + bb_[0]), relu(accA_[1] + bb_[1])); \
    wA_.y = pk2(relu(accA_[2] + bb_[2]), relu(accA_[3] + bb_[3])); \
    *(uint2*)(&H[c][16 * (nt) + 4 * g]) = wA_; \
    HB0 = pk2(relu(accB_[0] + bb_[0]), relu(accB_[1] + bb_[1])); \
    HB1 = pk2(relu(accB_[2] + bb_[2]), relu(accB_[3] + bb_[3])); }

#define HWB(nt, HB0, HB1) { \
    uint2 t_; t_.x = HB0; t_.y = HB1; \
    *(uint2*)(&H[c][16 * (nt) + 4 * g]) = t_; }

// DS-only scheduler wall: keeps LDS write->read program order (same-wave DS
// ops execute in order in the LDS pipe -- no lgkmcnt(0) drain needed), while
// letting VALU/SALU/MFMA/VMEM (mask 0x7F) migrate across for pipelining.
#define DSWALL __builtin_amdgcn_sched_barrier(0x7F)

// NOTE: second __launch_bounds__ arg behaves as min BLOCKS per CU on this
// toolchain. (1024,1): 16 waves/CU = 4/SIMD -> 128-VGPR cap.
__global__ __launch_bounds__(1024, 1)
void nerf_mfma(const float* __restrict__ points, const float* __restrict__ ws,
               const float* __restrict__ db3g, const float* __restrict__ rb2g,
               float* __restrict__ rgb_out, float* __restrict__ den_out) {
    // LDS: weights+consts 85504 B + per-wave H 16*16*136*2 = 69632 B -> 155136 B
    __shared__ __align__(16) ushort SB[42752];
    __shared__ __align__(16) ushort Hs[16][16][136];

    const float* P = ws;
    int tid = threadIdx.x;

    // ---- stage weight tables + consts into LDS (once per block) ----
    {
        const u32x4* src = (const u32x4*)(ws + 393216);
        u32x4* dst = (u32x4*)SB;
        for (int j = tid; j < 5344; j += 1024) dst[j] = src[j];
    }
    __syncthreads();

    const ushort* W1L = SB;                          // 24576 ushorts
    const ushort* W2L = SB + 24576;                  // 16384 ushorts
    const float*  Cl  = (const float*)(SB + 40960);  // BC | db2 | dW3 | rW2

    int wid = tid >> 6, lane = tid & 63;
    int c = lane & 15, g = lane >> 4;
    int g8 = 8 * g;
    ushort (*H)[136] = Hs[wid];
    int gw = blockIdx.x * 16 + wid;     // 16384 waves, 2 tiles each, 32 pts/tile

    float b3  = db3g[0];
    float rb0 = rb2g[0], rb1v = rb2g[1], rb2v = rb2g[2];

    #pragma unroll
    for (int it = 0; it < 2; ++it) {
        int pbase = (gw * 2 + it) * 32;

        // ---- features: lane (c,g) -> channels 8g..8g+7, points A=c, B=c+16 ----
        int ptA = pbase + c, ptB = pbase + c + 16;
        float xa = points[ptA * 3 + 0], ya = points[ptA * 3 + 1], za = points[ptA * 3 + 2];
        float xb = points[ptB * 3 + 0], yb = points[ptB * 3 + 1], zb = points[ptB * 3 + 2];
        short8 bfA0 = sample_frag(P, 0,      xa, ya, g8);
        short8 bfA1 = sample_frag(P, 131072, xa, za, g8);
        short8 bfA2 = sample_frag(P, 262144, ya, za, g8);
        short8 bfB0 = sample_frag(P, 0,      xb, yb, g8);
        short8 bfB1 = sample_frag(P, 131072, xb, zb, g8);
        short8 bfB2 = sample_frag(P, 262144, yb, zb, g8);

        // ---- layer1 rgb half (nt=8..15): fold rW2 immediately; w-reads shared ----
        float r0A = 0.f, r1A = 0.f, r2A = 0.f, r0B = 0.f, r1B = 0.f, r2B = 0.f;
        #pragma unroll 4
        for (int nt = 8; nt < 16; ++nt) {
            const ushort* wp = W1L + nt * 1536 + lane * 8;
            short8 a0 = *(const short8*)(wp);
            short8 a1 = *(const short8*)(wp + 512);
            short8 a2 = *(const short8*)(wp + 1024);
            f32x4 accA = {0.f,0.f,0.f,0.f}, accB = {0.f,0.f,0.f,0.f};
            accA = MFMA(a0, bfA0, accA); accB = MFMA(a0, bfB0, accB);
            accA = MFMA(a1, bfA1, accA); accB = MFMA(a1, bfB1, accB);
            accA = MFMA(a2, bfA2, accA); accB = MFMA(a2, bfB2, accB);
            int jo = (nt - 8) * 16 + 4 * g;
            f32x4 bb = *(const f32x4*)(Cl + 128 + jo);
            f32x4 w0 = *(const f32x4*)(Cl + 512 + jo);
            f32x4 w1 = *(const f32x4*)(Cl + 640 + jo);
            f32x4 w2 = *(const f32x4*)(Cl + 768 + jo);
            #pragma unroll
            for (int r = 0; r < 4; ++r) {
                float vA = relu(accA[r] + bb[r]);
                float vB = relu(accB[r] + bb[r]);
                r0A = fmaf(w0[r], vA, r0A); r0B = fmaf(w0[r], vB, r0B);
                r1A = fmaf(w1[r], vA, r1A); r1B = fmaf(w1[r], vB, r1B);
                r2A = fmaf(w2[r], vA, r2A); r2B = fmaf(w2[r], vB, r2B);
            }
        }
        // rgb heads now (kills racc early)
        {
            float v0 = r0A, v1 = r1A, v2 = r2A;
            v0 += __shfl_xor(v0, 16, 64); v0 += __shfl_xor(v0, 32, 64);
            v1 += __shfl_xor(v1, 16, 64); v1 += __shfl_xor(v1, 32, 64);
            v2 += __shfl_xor(v2, 16, 64); v2 += __shfl_xor(v2, 32, 64);
            if (g == 0) {
                rgb_out[ptA * 3 + 0] = 1.0f / (1.0f + expf(-(v0 + rb0)));
                rgb_out[ptA * 3 + 1] = 1.0f / (1.0f + expf(-(v1 + rb1v)));
                rgb_out[ptA * 3 + 2] = 1.0f / (1.0f + expf(-(v2 + rb2v)));
            }
        }
        {
            float v0 = r0B, v1 = r1B, v2 = r2B;
            v0 += __shfl_xor(v0, 16, 64); v0 += __shfl_xor(v0, 32, 64);
            v1 += __shfl_xor(v1, 16, 64); v1 += __shfl_xor(v1, 32, 64);
            v2 += __shfl_xor(v2, 16, 64); v2 += __shfl_xor(v2, 32, 64);
            if (g == 0) {
                rgb_out[ptB * 3 + 0] = 1.0f / (1.0f + expf(-(v0 + rb0)));
                rgb_out[ptB * 3 + 1] = 1.0f / (1.0f + expf(-(v1 + rb1v)));
                rgb_out[ptB * 3 + 2] = 1.0f / (1.0f + expf(-(v2 + rb2v)));
            }
        }

        // ---- layer1 density half (nt=0..7): A -> H, B -> named regs ----
        unsigned hB0a, hB0b, hB1a, hB1b, hB2a, hB2b, hB3a, hB3b;
        unsigned hB4a, hB4b, hB5a, hB5b, hB6a, hB6b, hB7a, hB7b;
        DNT(0, hB0a, hB0b) DNT(1, hB1a, hB1b) DNT(2, hB2a, hB2b) DNT(3, hB3a, hB3b)
        DNT(4, hB4a, hB4b) DNT(5, hB5a, hB5b) DNT(6, hB6a, hB6b) DNT(7, hB7a, hB7b)

        DSWALL;   // all A-writes issue before A-reads (same-wave LDS is in-order)
        short8 b2A0 = *(const short8*)(&H[c][g8]);
        short8 b2A1 = *(const short8*)(&H[c][32 + g8]);
        short8 b2A2 = *(const short8*)(&H[c][64 + g8]);
        short8 b2A3 = *(const short8*)(&H[c][96 + g8]);
        DSWALL;   // A-reads issue before B overwrites
        HWB(0, hB0a, hB0b) HWB(1, hB1a, hB1b) HWB(2, hB2a, hB2b) HWB(3, hB3a, hB3b)
        HWB(4, hB4a, hB4b) HWB(5, hB5a, hB5b) HWB(6, hB6a, hB6b) HWB(7, hB7a, hB7b)
        DSWALL;   // B-writes issue before B-reads
        short8 b2B0 = *(const short8*)(&H[c][g8]);
        short8 b2B1 = *(const short8*)(&H[c][32 + g8]);
        short8 b2B2 = *(const short8*)(&H[c][64 + g8]);
        short8 b2B3 = *(const short8*)(&H[c][96 + g8]);
        DSWALL;   // B-reads issue before next tile's A-writes

        // ---- layer2 + density fold: one A-frag read feeds 2 MFMAs ----
        float daccA = 0.f, daccB = 0.f;
        #pragma unroll 2
        for (int nt2 = 0; nt2 < 8; ++nt2) {
            const ushort* wp = W2L + nt2 * 2048 + lane * 8;
            short8 a0 = *(const short8*)(wp);
            short8 a1 = *(const short8*)(wp + 512);
            short8 a2 = *(const short8*)(wp + 1024);
            short8 a3 = *(const short8*)(wp + 1536);
            f32x4 accA = {0.f,0.f,0.f,0.f}, accB = {0.f,0.f,0.f,0.f};
            accA = MFMA(a0, b2A0, accA); accB = MFMA(a0, b2B0, accB);
            accA = MFMA(a1, b2A1, accA); accB = MFMA(a1, b2B1, accB);
            accA = MFMA(a2, b2A2, accA); accB = MFMA(a2, b2B2, accB);
            accA = MFMA(a3, b2A3, accA); accB = MFMA(a3, b2B3, accB);
            f32x4 bb = *(const f32x4*)(Cl + 256 + nt2 * 16 + 4 * g);
            f32x4 w3 = *(const f32x4*)(Cl + 384 + nt2 * 16 + 4 * g);
            #pragma unroll
            for (int r = 0; r < 4; ++r) {
                daccA = fmaf(w3[r], relu(accA[r] + bb[r]), daccA);
                daccB = fmaf(w3[r], relu(accB[r] + bb[r]), daccB);
            }
        }

        // ---- density heads ----
        {
            float v = daccA; v += __shfl_xor(v, 16, 64); v += __shfl_xor(v, 32, 64); v += b3;
            float sp = fmaxf(v, 0.0f) + log1pf(expf(-fabsf(v)));
            if (g == 0) den_out[ptA] = sp;
        }
        {
            float v = daccB; v += __shfl_xor(v, 16, 64); v += __shfl_xor(v, 32, 64); v += b3;
            float sp = fmaxf(v, 0.0f) + log1pf(expf(-fabsf(v)));
            if (g == 0) den_out[ptB] = sp;
        }
    }
}

extern "C" void kernel_launch(void* const* d_in, const int* in_sizes, int n_in,
                              void* d_out, int out_size, void* d_ws, size_t ws_size,
                              hipStream_t stream) {
    const float* points = (const float*)d_in[0];
    const float* planes = (const float*)d_in[1];
    const float* dW1    = (const float*)d_in[2];
    const float* db1    = (const float*)d_in[3];
    const float* dW2    = (const float*)d_in[4];
    const float* db2    = (const float*)d_in[5];
    const float* dW3    = (const float*)d_in[6];
    const float* db3    = (const float*)d_in[7];
    const float* rW1    = (const float*)d_in[8];
    const float* rb1    = (const float*)d_in[9];
    const float* rW2    = (const float*)d_in[10];
    const float* rb2    = (const float*)d_in[11];

    float* out     = (float*)d_out;
    float* rgb_out = out;                 // 3*NPTS floats
    float* den_out = out + 3 * NPTS;      // NPTS floats
    float* ws      = (float*)d_ws;

    prepass<<<1536, 256, 0, stream>>>(planes, dW1, rW1, dW2, db1, rb1,
                                      db2, dW3, rW2, ws);
    nerf_mfma<<<1024, 1024, 0, stream>>>(points, ws, db3, rb2, rgb_out, den_out);
}

// Round 13
// 214.370 us; speedup vs baseline: 1.0673x; 1.0399x over previous
//
#include <hip/hip_runtime.h>
#include <hip/hip_bf16.h>
#include <math.h>

#define RR 64
#define CC 32
#define NPTS (4*262144)

typedef __attribute__((ext_vector_type(8))) short short8;
typedef __attribute__((ext_vector_type(4))) float f32x4;
typedef __attribute__((ext_vector_type(4))) unsigned int u32x4;

static __device__ inline ushort f2bf(float x) {
    return __builtin_bit_cast(ushort, __float2bfloat16(x));
}
static __device__ inline uint32_t pk2(float a, float b) {
    return (uint32_t)f2bf(a) | ((uint32_t)f2bf(b) << 16);
}
static __device__ inline f32x4 relu4(f32x4 v) {
    f32x4 z = {0.f, 0.f, 0.f, 0.f};
    return __builtin_elementwise_max(v, z);
}
static __device__ inline float hsum4(f32x4 v) {
    return (v[0] + v[1]) + (v[2] + v[3]);
}

// ws layout:
//   float  Pcl[3*64*64*32]   @ 0          channel-last fp32 planes [p][y][x][ch]
//   ushort W1T[24576]        @ 393216 f   layer1 A-frag table [nt][p][lane][e]
//   ushort W2T[16384]        follows      layer2 A-frag table [nt2][kt2][lane][e]
//   float  CWS[896]          follows      BC[256]=db1|rb1 | db2[128] | dW3[128] | rW2[384]
// W1T..CWS = 85504 B, staged to LDS once per block.

__global__ void prepass(const float* __restrict__ planes,
                        const float* __restrict__ dW1, const float* __restrict__ rW1,
                        const float* __restrict__ dW2,
                        const float* __restrict__ db1, const float* __restrict__ rb1,
                        const float* __restrict__ db2, const float* __restrict__ dW3,
                        const float* __restrict__ rW2,
                        float* __restrict__ ws) {
    int tid = blockIdx.x * blockDim.x + threadIdx.x;
    ushort* W1T = (ushort*)(ws + 393216);
    ushort* W2T = W1T + 24576;
    float*  CWS = ws + 393216 + 20480;

    if (tid < 3 * CC * RR * RR) {
        int x = tid % RR, y = (tid / RR) % RR, ch = (tid / (RR * RR)) % CC, p = tid / (CC * RR * RR);
        ws[((p * RR + y) * RR + x) * CC + ch] = planes[tid];
    }
    if (tid < 24576) {   // W1T: tid = ((nt*3+p)*64 + l)*8 + e
        int e = tid & 7, l = (tid >> 3) & 63, rem = tid >> 9;
        int p = rem % 3, nt = rem / 3;
        int j = nt * 16 + (l & 15);
        int k = p * 32 + (l >> 4) * 8 + e;
        float v = (j < 128) ? dW1[j * 96 + k] : rW1[(j - 128) * 96 + k];
        W1T[tid] = f2bf(v);
    }
    if (tid < 16384) {   // W2T: tid = ((nt2*4+kt2)*64 + l)*8 + e
        int e = tid & 7, l = (tid >> 3) & 63, rem = tid >> 9;
        int kt2 = rem & 3, nt2 = rem >> 2;
        int j2 = nt2 * 16 + (l & 15);
        int k = kt2 * 32 + (l >> 4) * 8 + e;
        W2T[tid] = f2bf(dW2[j2 * 128 + k]);
    }
    if (tid < 256) CWS[tid]       = (tid < 128) ? db1[tid] : rb1[tid - 128];
    if (tid < 128) CWS[256 + tid] = db2[tid];
    if (tid < 128) CWS[384 + tid] = dW3[tid];
    if (tid < 384) CWS[512 + tid] = rW2[tid];
}

// Bilinear-sample 8 channels (8g..8g+7) of one plane at (cx,cy), packed as a
// bf16 MFMA B-fragment. Vector (packed-f32) interpolation arithmetic.
static __device__ inline short8 sample_frag(const float* __restrict__ P,
                                            int plane_base, float cx, float cy, int g8) {
    float ix = (cx + 1.0f) * 31.5f; ix = fminf(fmaxf(ix, 0.0f), 63.0f);
    float iy = (cy + 1.0f) * 31.5f; iy = fminf(fmaxf(iy, 0.0f), 63.0f);
    int x0 = (int)ix, y0 = (int)iy;
    int x1 = min(x0 + 1, 63), y1 = min(y0 + 1, 63);
    float wx = ix - (float)x0, wy = iy - (float)y0;
    float w00 = (1.0f - wx) * (1.0f - wy), w01 = wx * (1.0f - wy);
    float w10 = (1.0f - wx) * wy,          w11 = wx * wy;
    int b00 = plane_base + (y0 * 64 + x0) * 32 + g8;
    int b01 = plane_base + (y0 * 64 + x1) * 32 + g8;
    int b10 = plane_base + (y1 * 64 + x0) * 32 + g8;
    int b11 = plane_base + (y1 * 64 + x1) * 32 + g8;
    f32x4 a0 = *(const f32x4*)(P + b00), a1 = *(const f32x4*)(P + b00 + 4);
    f32x4 c0 = *(const f32x4*)(P + b01), c1 = *(const f32x4*)(P + b01 + 4);
    f32x4 d0 = *(const f32x4*)(P + b10), d1 = *(const f32x4*)(P + b10 + 4);
    f32x4 e0 = *(const f32x4*)(P + b11), e1 = *(const f32x4*)(P + b11 + 4);
    f32x4 flo = a0 * w00 + c0 * w01 + d0 * w10 + e0 * w11;   // v_pk_fma_f32
    f32x4 fhi = a1 * w00 + c1 * w01 + d1 * w10 + e1 * w11;
    u32x4 uu;
    uu[0] = pk2(flo[0], flo[1]); uu[1] = pk2(flo[2], flo[3]);
    uu[2] = pk2(fhi[0], fhi[1]); uu[3] = pk2(fhi[2], fhi[3]);
    return __builtin_bit_cast(short8, uu);
}

#define MFMA(a, b, c) __builtin_amdgcn_mfma_f32_16x16x32_bf16((a), (b), (c), 0, 0, 0)

// Density layer-1 tile nt for BOTH point halves: one A-frag read feeds 2 MFMAs.
// A-half result -> H (LDS); B-half result -> two named u32 regs (written later).
#define DNT(nt, HB0, HB1) { \
    const ushort* wp_ = W1L + (nt) * 1536 + lane * 8; \
    short8 a0_ = *(const short8*)(wp_); \
    short8 a1_ = *(const short8*)(wp_ + 512); \
    short8 a2_ = *(const short8*)(wp_ + 1024); \
    f32x4 accA_ = {0.f,0.f,0.f,0.f}, accB_ = {0.f,0.f,0.f,0.f}; \
    accA_ = MFMA(a0_, bfA0, accA_); accB_ = MFMA(a0_, bfB0, accB_); \
    accA_ = MFMA(a1_, bfA1, accA_); accB_ = MFMA(a1_, bfB1, accB_); \
    accA_ = MFMA(a2_, bfA2, accA_); accB_ = MFMA(a2_, bfB2, accB_); \
    f32x4 bb_ = *(const f32x4*)(Cl + (nt) * 16 + 4 * g); \
    f32x4 vA_ = relu4(accA_ + bb_); \
    f32x4 vB_ = relu4(accB_ + bb_); \
    uint2 wA_; \
    wA_.x = pk2(vA_[0], vA_[1]); \
    wA_.y = pk2(vA_[2], vA_[3]); \
    *(uint2*)(&H[c][16 * (nt) + 4 * g]) = wA_; \
    HB0 = pk2(vB_[0], vB_[1]); \
    HB1 = pk2(vB_[2], vB_[3]); }

#define HWB(nt, HB0, HB1) { \
    uint2 t_; t_.x = HB0; t_.y = HB1; \
    *(uint2*)(&H[c][16 * (nt) + 4 * g]) = t_; }

// DS-only scheduler wall: keeps same-wave LDS write->read program order while
// letting VALU/SALU/MFMA/VMEM (mask 0x7F) migrate across for pipelining.
#define DSWALL __builtin_amdgcn_sched_barrier(0x7F)

// NOTE: second __launch_bounds__ arg behaves as min BLOCKS per CU on this
// toolchain. (1024,1): 16 waves/CU = 4/SIMD -> 128-VGPR cap.
__global__ __launch_bounds__(1024, 1)
void nerf_mfma(const float* __restrict__ points, const float* __restrict__ ws,
               const float* __restrict__ db3g, const float* __restrict__ rb2g,
               float* __restrict__ rgb_out, float* __restrict__ den_out) {
    // LDS: weights+consts 85504 B + per-wave H 16*16*136*2 = 69632 B -> 155136 B
    __shared__ __align__(16) ushort SB[42752];
    __shared__ __align__(16) ushort Hs[16][16][136];

    const float* P = ws;
    int tid = threadIdx.x;

    // ---- stage weight tables + consts into LDS (once per block) ----
    {
        const u32x4* src = (const u32x4*)(ws + 393216);
        u32x4* dst = (u32x4*)SB;
        for (int j = tid; j < 5344; j += 1024) dst[j] = src[j];
    }
    __syncthreads();

    const ushort* W1L = SB;                          // 24576 ushorts
    const ushort* W2L = SB + 24576;                  // 16384 ushorts
    const float*  Cl  = (const float*)(SB + 40960);  // BC | db2 | dW3 | rW2

    int wid = tid >> 6, lane = tid & 63;
    int c = lane & 15, g = lane >> 4;
    int g8 = 8 * g;
    ushort (*H)[136] = Hs[wid];
    int gw = blockIdx.x * 16 + wid;     // 16384 waves, 2 tiles each, 32 pts/tile

    float b3  = db3g[0];
    float rb0 = rb2g[0], rb1v = rb2g[1], rb2v = rb2g[2];

    #pragma unroll
    for (int it = 0; it < 2; ++it) {
        int pbase = (gw * 2 + it) * 32;

        // ---- features: lane (c,g) -> channels 8g..8g+7, points A=c, B=c+16 ----
        int ptA = pbase + c, ptB = pbase + c + 16;
        float xa = points[ptA * 3 + 0], ya = points[ptA * 3 + 1], za = points[ptA * 3 + 2];
        float xb = points[ptB * 3 + 0], yb = points[ptB * 3 + 1], zb = points[ptB * 3 + 2];
        short8 bfA0 = sample_frag(P, 0,      xa, ya, g8);
        short8 bfA1 = sample_frag(P, 131072, xa, za, g8);
        short8 bfA2 = sample_frag(P, 262144, ya, za, g8);
        short8 bfB0 = sample_frag(P, 0,      xb, yb, g8);
        short8 bfB1 = sample_frag(P, 131072, xb, zb, g8);
        short8 bfB2 = sample_frag(P, 262144, yb, zb, g8);

        // ---- layer1 rgb half (nt=8..15): fold rW2 immediately, vector accs ----
        f32x4 r0A4 = {0.f,0.f,0.f,0.f}, r1A4 = {0.f,0.f,0.f,0.f}, r2A4 = {0.f,0.f,0.f,0.f};
        f32x4 r0B4 = {0.f,0.f,0.f,0.f}, r1B4 = {0.f,0.f,0.f,0.f}, r2B4 = {0.f,0.f,0.f,0.f};
        #pragma unroll 4
        for (int nt = 8; nt < 16; ++nt) {
            const ushort* wp = W1L + nt * 1536 + lane * 8;
            short8 a0 = *(const short8*)(wp);
            short8 a1 = *(const short8*)(wp + 512);
            short8 a2 = *(const short8*)(wp + 1024);
            f32x4 accA = {0.f,0.f,0.f,0.f}, accB = {0.f,0.f,0.f,0.f};
            accA = MFMA(a0, bfA0, accA); accB = MFMA(a0, bfB0, accB);
            accA = MFMA(a1, bfA1, accA); accB = MFMA(a1, bfB1, accB);
            accA = MFMA(a2, bfA2, accA); accB = MFMA(a2, bfB2, accB);
            int jo = (nt - 8) * 16 + 4 * g;
            f32x4 bb = *(const f32x4*)(Cl + 128 + jo);
            f32x4 w0 = *(const f32x4*)(Cl + 512 + jo);
            f32x4 w1 = *(const f32x4*)(Cl + 640 + jo);
            f32x4 w2 = *(const f32x4*)(Cl + 768 + jo);
            f32x4 vA = relu4(accA + bb);
            f32x4 vB = relu4(accB + bb);
            r0A4 += w0 * vA; r0B4 += w0 * vB;
            r1A4 += w1 * vA; r1B4 += w1 * vB;
            r2A4 += w2 * vA; r2B4 += w2 * vB;
        }
        // rgb heads now (kills racc early)
        {
            float v0 = hsum4(r0A4), v1 = hsum4(r1A4), v2 = hsum4(r2A4);
            v0 += __shfl_xor(v0, 16, 64); v0 += __shfl_xor(v0, 32, 64);
            v1 += __shfl_xor(v1, 16, 64); v1 += __shfl_xor(v1, 32, 64);
            v2 += __shfl_xor(v2, 16, 64); v2 += __shfl_xor(v2, 32, 64);
            if (g == 0) {
                rgb_out[ptA * 3 + 0] = 1.0f / (1.0f + expf(-(v0 + rb0)));
                rgb_out[ptA * 3 + 1] = 1.0f / (1.0f + expf(-(v1 + rb1v)));
                rgb_out[ptA * 3 + 2] = 1.0f / (1.0f + expf(-(v2 + rb2v)));
            }
        }
        {
            float v0 = hsum4(r0B4), v1 = hsum4(r1B4), v2 = hsum4(r2B4);
            v0 += __shfl_xor(v0, 16, 64); v0 += __shfl_xor(v0, 32, 64);
            v1 += __shfl_xor(v1, 16, 64); v1 += __shfl_xor(v1, 32, 64);
            v2 += __shfl_xor(v2, 16, 64); v2 += __shfl_xor(v2, 32, 64);
            if (g == 0) {
                rgb_out[ptB * 3 + 0] = 1.0f / (1.0f + expf(-(v0 + rb0)));
                rgb_out[ptB * 3 + 1] = 1.0f / (1.0f + expf(-(v1 + rb1v)));
                rgb_out[ptB * 3 + 2] = 1.0f / (1.0f + expf(-(v2 + rb2v)));
            }
        }

        // ---- layer1 density half (nt=0..7): A -> H, B -> named regs ----
        unsigned hB0a, hB0b, hB1a, hB1b, hB2a, hB2b, hB3a, hB3b;
        unsigned hB4a, hB4b, hB5a, hB5b, hB6a, hB6b, hB7a, hB7b;
        DNT(0, hB0a, hB0b) DNT(1, hB1a, hB1b) DNT(2, hB2a, hB2b) DNT(3, hB3a, hB3b)
        DNT(4, hB4a, hB4b) DNT(5, hB5a, hB5b) DNT(6, hB6a, hB6b) DNT(7, hB7a, hB7b)

        DSWALL;   // all A-writes issue before A-reads (same-wave LDS is in-order)
        short8 b2A0 = *(const short8*)(&H[c][g8]);
        short8 b2A1 = *(const short8*)(&H[c][32 + g8]);
        short8 b2A2 = *(const short8*)(&H[c][64 + g8]);
        short8 b2A3 = *(const short8*)(&H[c][96 + g8]);
        DSWALL;   // A-reads issue before B overwrites
        HWB(0, hB0a, hB0b) HWB(1, hB1a, hB1b) HWB(2, hB2a, hB2b) HWB(3, hB3a, hB3b)
        HWB(4, hB4a, hB4b) HWB(5, hB5a, hB5b) HWB(6, hB6a, hB6b) HWB(7, hB7a, hB7b)
        DSWALL;   // B-writes issue before B-reads
        short8 b2B0 = *(const short8*)(&H[c][g8]);
        short8 b2B1 = *(const short8*)(&H[c][32 + g8]);
        short8 b2B2 = *(const short8*)(&H[c][64 + g8]);
        short8 b2B3 = *(const short8*)(&H[c][96 + g8]);
        DSWALL;   // B-reads issue before next tile's A-writes

        // ---- layer2 + density fold: vector accumulators ----
        f32x4 dA4 = {0.f,0.f,0.f,0.f}, dB4 = {0.f,0.f,0.f,0.f};
        #pragma unroll 2
        for (int nt2 = 0; nt2 < 8; ++nt2) {
            const ushort* wp = W2L + nt2 * 2048 + lane * 8;
            short8 a0 = *(const short8*)(wp);
            short8 a1 = *(const short8*)(wp + 512);
            short8 a2 = *(const short8*)(wp + 1024);
            short8 a3 = *(const short8*)(wp + 1536);
            f32x4 accA = {0.f,0.f,0.f,0.f}, accB = {0.f,0.f,0.f,0.f};
            accA = MFMA(a0, b2A0, accA); accB = MFMA(a0, b2B0, accB);
            accA = MFMA(a1, b2A1, accA); accB = MFMA(a1, b2B1, accB);
            accA = MFMA(a2, b2A2, accA); accB = MFMA(a2, b2B2, accB);
            accA = MFMA(a3, b2A3, accA); accB = MFMA(a3, b2B3, accB);
            f32x4 bb = *(const f32x4*)(Cl + 256 + nt2 * 16 + 4 * g);
            f32x4 w3 = *(const f32x4*)(Cl + 384 + nt2 * 16 + 4 * g);
            dA4 += w3 * relu4(accA + bb);
            dB4 += w3 * relu4(accB + bb);
        }

        // ---- density heads ----
        {
            float v = hsum4(dA4);
            v += __shfl_xor(v, 16, 64); v += __shfl_xor(v, 32, 64); v += b3;
            float sp = fmaxf(v, 0.0f) + log1pf(expf(-fabsf(v)));
            if (g == 0) den_out[ptA] = sp;
        }
        {
            float v = hsum4(dB4);
            v += __shfl_xor(v, 16, 64); v += __shfl_xor(v, 32, 64); v += b3;
            float sp = fmaxf(v, 0.0f) + log1pf(expf(-fabsf(v)));
            if (g == 0) den_out[ptB] = sp;
        }
    }
}

extern "C" void kernel_launch(void* const* d_in, const int* in_sizes, int n_in,
                              void* d_out, int out_size, void* d_ws, size_t ws_size,
                              hipStream_t stream) {
    const float* points = (const float*)d_in[0];
    const float* planes = (const float*)d_in[1];
    const float* dW1    = (const float*)d_in[2];
    const float* db1    = (const float*)d_in[3];
    const float* dW2    = (const float*)d_in[4];
    const float* db2    = (const float*)d_in[5];
    const float* dW3    = (const float*)d_in[6];
    const float* db3    = (const float*)d_in[7];
    const float* rW1    = (const float*)d_in[8];
    const float* rb1    = (const float*)d_in[9];
    const float* rW2    = (const float*)d_in[10];
    const float* rb2    = (const float*)d_in[11];

    float* out     = (float*)d_out;
    float* rgb_out = out;                 // 3*NPTS floats
    float* den_out = out + 3 * NPTS;      // NPTS floats
    float* ws      = (float*)d_ws;

    prepass<<<1536, 256, 0, stream>>>(planes, dW1, rW1, dW2, db1, rb1,
                                      db2, dW3, rW2, ws);
    nerf_mfma<<<1024, 1024, 0, stream>>>(points, ws, db3, rb2, rgb_out, den_out);
}